// Round 11
// baseline (182.936 us; speedup 1.0000x reference)
//
#include <hip/hip_runtime.h>
#include <cstdint>
#include <cstddef>

// Problem constants (fixed by the reference)
#define BB 4
#define TT 2048
#define DDIM 1024
#define KCODES 8192
#define MROWS (BB*TT)          // 8192
// reduce margin: 0.5 (true approx-error bound, proven R8) + 2x1.0 quantization
#define MARGIN 2.5f

typedef _Float16 f16;
typedef _Float16 half8 __attribute__((ext_vector_type(8)));
typedef _Float16 half4v __attribute__((ext_vector_type(4)));
typedef float f32x4 __attribute__((ext_vector_type(4)));
typedef unsigned long long u64;
typedef unsigned int u32;

// ---- helpers -------------------------------------------------------------

// quantized packed score: scores are provably positive (~[480,1600]), so the
// raw float bits are monotone; keep top 19 bits (ulp <= 1.0) and pack the
// 13-bit col index in the low bits. min(packed) = (min score, lowest col).
__device__ __forceinline__ u32 packQ(float s, u32 col){
  return (__float_as_uint(s) & 0xFFFFE000u) | col;
}
__device__ __forceinline__ float unpackQ(u32 m){
  return __uint_as_float(m & 0xFFFFE000u);
}

// packed exact score for the fp32 fallback path
__device__ __forceinline__ u64 packScore(float s, u32 idx){
  u32 b = __float_as_uint(s);
  b ^= (b & 0x80000000u) ? 0xFFFFFFFFu : 0x80000000u;
  return ((u64)b << 32) | (u64)idx;
}

// async global->LDS, 16B per lane; lds base must be wave-uniform (HW writes lane l at +16*l)
__device__ __forceinline__ void glds16(const void* g, void* l){
  __builtin_amdgcn_global_load_lds(
      (const __attribute__((address_space(1))) unsigned int*)g,
      (__attribute__((address_space(3))) unsigned int*)l, 16, 0, 0);
}

// ---- prep: x -> Ahi (f16), cb -> Bhi (f16) + exact fp32 ||c||^2 ----------
__global__ void prep_all(const float* __restrict__ x, const float* __restrict__ cb,
                         f16* __restrict__ Ahi, f16* __restrict__ Bhi,
                         float* __restrict__ csq){
  const int row = blockIdx.x;            // 0..16383
  const int tid = threadIdx.x;
  if (row < MROWS){
    const float4 v = ((const float4*)x)[(size_t)row * 256 + tid];
    half4v hi;
    hi[0] = (f16)v.x; hi[1] = (f16)v.y; hi[2] = (f16)v.z; hi[3] = (f16)v.w;
    ((half4v*)Ahi)[(size_t)row * 256 + tid] = hi;
  } else {
    const int r = row - MROWS;
    const float4 v = ((const float4*)cb)[(size_t)r * 256 + tid];
    half4v hi;
    hi[0] = (f16)v.x; hi[1] = (f16)v.y; hi[2] = (f16)v.z; hi[3] = (f16)v.w;
    ((half4v*)Bhi)[(size_t)r * 256 + tid] = hi;
    float s = v.x*v.x + v.y*v.y + v.z*v.z + v.w*v.w;
    #pragma unroll
    for (int m = 32; m; m >>= 1) s += __shfl_xor(s, m, 64);
    __shared__ float red[4];
    if ((tid & 63) == 0) red[tid >> 6] = s;
    __syncthreads();
    if (tid == 0) csq[r] = red[0] + red[1] + red[2] + red[3];
  }
}

// ---- pass 1: approx GEMM (hi*hi, 16 K-steps) + per-block top-2 -----------
// 256x256 tile, BK=64, 8 waves (4m x 2n, 512 thr), SINGLE LDS buffer, the
// PROVEN strict schedule: sync -> stage -> sync -> compute (no DMA/ds_read
// overlap, ever — R3-R6 lesson). Per wave: 64x128 output (acc[4][8]),
// 8 glds16 + 24 ds_read_b128 + 64 MFMA per K-step.
// XOR slot swizzle (phys 16B slot = logical ^ (row&7)) on both sides.
// T1 XCD-aware mapping: each XCD owns 4 contiguous A-panels, bn-major walk.
// Epilogue: quantized u32 top-2 (proven R9/R10), two half-passes over rows,
// blk2 panels = 128 cols via bn*2+half.
__global__ __launch_bounds__(512, 2) void vq_gemm(
    const f16* __restrict__ Ahi, const f16* __restrict__ Bhi,
    const float* __restrict__ csq, u64* __restrict__ blk2)
{
  __shared__ f16 smem[2 * 256 * 64];              // 64 KB
  f16* sA = smem;                                 // [256*64]
  f16* sB = smem + 256 * 64;                      // [256*64]

  const int tid  = threadIdx.x;
  const int lane = tid & 63;
  const int wid  = tid >> 6;            // 0..7
  const int wm   = wid >> 1;            // 0..3 (M quarter, 64 rows)
  const int wn   = wid & 1;             // 0..1 (N half, 128 cols)

  // T1: XCD-aware tile mapping (bijective on 32x32 grid)
  const int lin = blockIdx.y * 32 + blockIdx.x;   // 0..1023, x-fastest
  const int xcd = lin & 7;
  const int pos = lin >> 3;                       // 0..127
  const int bm  = xcd * 4 + (pos & 3);            // 4 contiguous A-panels/XCD
  const int bn  = pos >> 2;                       // 0..31, bn-major walk

  const int l15 = lane & 15, lk = lane >> 4;

  f32x4 acc[4][8];
  #pragma unroll
  for (int i = 0; i < 4; ++i)
    #pragma unroll
    for (int j = 0; j < 8; ++j)
      acc[i][j] = (f32x4)0.0f;

  // staging source geometry (pre-swizzled global column), proven R2
  const int srow = lane >> 3;                     // 0..7
  const int scol = (((lane & 7) ^ srow) * 8);     // halves, swizzled source

  for (int kt = 0; kt < 16; ++kt){
    const int kin = kt * 64;

    __syncthreads();  // previous compute done before LDS overwrite
    // A: 32 chunks of 8 rows; wave stages 4
    #pragma unroll
    for (int j = 0; j < 4; ++j){
      const int rb = (wid * 4 + j) * 8;
      glds16(Ahi + (size_t)(bm * 256 + rb + srow) * DDIM + kin + scol,
             sA + rb * 64);
    }
    // B: 32 chunks; wave stages 4
    #pragma unroll
    for (int j = 0; j < 4; ++j){
      const int rb = (wid * 4 + j) * 8;
      glds16(Bhi + (size_t)(bn * 256 + rb + srow) * DDIM + kin + scol,
             sB + rb * 64);
    }
    __syncthreads();  // staging visible (compiler drains vmcnt before s_barrier)

    #pragma unroll
    for (int kk = 0; kk < 2; ++kk){
      half8 a[4], b[8];
      #pragma unroll
      for (int mf = 0; mf < 4; ++mf){
        const int r = wm * 64 + mf * 16 + l15;
        const int p = (kk * 4 + lk) ^ (r & 7);
        a[mf] = *(const half8*)&sA[r * 64 + p * 8];
      }
      #pragma unroll
      for (int nf = 0; nf < 8; ++nf){
        const int r = wn * 128 + nf * 16 + l15;
        const int p = (kk * 4 + lk) ^ (r & 7);
        b[nf] = *(const half8*)&sB[r * 64 + p * 8];
      }
      #pragma unroll
      for (int mf = 0; mf < 4; ++mf)
        #pragma unroll
        for (int nf = 0; nf < 8; ++nf)
          acc[mf][nf] = __builtin_amdgcn_mfma_f32_16x16x32_f16(a[mf], b[nf], acc[mf][nf], 0, 0, 0);
    }
  }

  // ---- epilogue: per-(row,128-col-panel) top-2 (quantized u32) ----
  __syncthreads();                                 // loop's LDS reads done
  u32* mrg = (u32*)smem;                           // [128][68] u32 = 34816 B

  float csqv[8];
  u32 gcolv[8];
  #pragma unroll
  for (int nf = 0; nf < 8; ++nf){
    gcolv[nf] = bn * 256 + wn * 128 + nf * 16 + l15;
    csqv[nf]  = csq[gcolv[nf]];
  }
  #pragma unroll
  for (int H = 0; H < 2; ++H){
    if ((wm >> 1) == H){
      #pragma unroll
      for (int mf = 0; mf < 4; ++mf){
        #pragma unroll
        for (int r = 0; r < 4; ++r){
          const int lrow = (wm & 1) * 64 + mf * 16 + lk * 4 + r;  // 0..127 in half
          u32 b1 = 0xFFFFFFFFu, b2 = 0xFFFFFFFFu;
          #pragma unroll
          for (int nf = 0; nf < 8; ++nf){
            const u32 p = packQ(csqv[nf] - 2.0f * acc[mf][nf][r], gcolv[nf]);
            if (p < b1){ b2 = b1; b1 = p; } else if (p < b2){ b2 = p; }
          }
          *(uint2*)&mrg[lrow * 68 + (wn * 16 + l15) * 2] = make_uint2(b1, b2);
        }
      }
    }
    __syncthreads();
    if (tid < 256){
      const int r = tid >> 1, h = tid & 1;         // row in half, 128-col panel
      u32 b1 = 0xFFFFFFFFu, b2 = 0xFFFFFFFFu;
      const uint4* rowp = (const uint4*)&mrg[r * 68 + h * 32];
      #pragma unroll
      for (int j = 0; j < 8; ++j){
        const uint4 q = rowp[j];
        u32 vv[4] = {q.x, q.y, q.z, q.w};
        #pragma unroll
        for (int s = 0; s < 4; ++s){
          const u32 v = vv[s];
          if (v < b1){ b2 = b1; b1 = v; } else if (v < b2){ b2 = v; }
        }
      }
      blk2[(size_t)(bm * 256 + H * 128 + r) * 64 + bn * 2 + h] = (u64)b1 | ((u64)b2 << 32);
    }
    __syncthreads();
  }
}

// ---- pass 2 (fused): candidate extraction + exact refine + gather --------
__global__ void refine_gather(const float* __restrict__ x, const float* __restrict__ cb,
                              const float* __restrict__ emb, const float* __restrict__ pe,
                              const float* __restrict__ csq,
                              const u64* __restrict__ blk2,
                              float* __restrict__ out){
  const int row = blockIdx.x, tid = threadIdx.x;
  const int wid = tid >> 6, lane = tid & 63;
  __shared__ u32 scand[8];
  __shared__ u32 scnt;
  __shared__ float red[4];
  __shared__ u32 swin;

  // wave 0: reduce 64 block-top-2s -> global min + candidates within MARGIN
  if (wid == 0){
    const u64 v = blk2[(size_t)row * 64 + lane];
    u32 c1 = (u32)v, c2 = (u32)(v >> 32);
    float thr = 0.f;
    u32 count = 0;
    for (int k = 0; k < 8; ++k){
      u32 loc = (c1 < c2) ? c1 : c2;
      #pragma unroll
      for (int m = 1; m < 64; m <<= 1){
        const u32 o = __shfl_xor(loc, m, 64);
        loc = (o < loc) ? o : loc;
      }
      const float sf = unpackQ(loc);
      if (k == 0) thr = sf + MARGIN;
      else if (sf > thr) break;
      if (lane == 0) scand[k] = loc & 0x1FFFu;
      ++count;
      if (c1 == loc) c1 = 0xFFFFFFFFu;
      if (c2 == loc) c2 = 0xFFFFFFFFu;
    }
    if (lane == 0) scnt = count;
  }
  __syncthreads();

  u32 widx = scand[0];
  const u32 n = scnt;
  if (n > 1){
    const float4 xv = ((const float4*)x)[(size_t)row * 256 + tid];
    float bd2 = 0.f; u32 bidx = 0;
    for (u32 k = 0; k < n; ++k){
      const u32 c = scand[k];
      const float4 cv = ((const float4*)cb)[(size_t)c * 256 + tid];
      float p = xv.x*cv.x + xv.y*cv.y + xv.z*cv.z + xv.w*cv.w;
      #pragma unroll
      for (int m = 32; m; m >>= 1) p += __shfl_xor(p, m, 64);
      if (lane == 0) red[wid] = p;
      __syncthreads();
      if (tid == 0){
        const float d2 = csq[c] - 2.0f * (red[0] + red[1] + red[2] + red[3]);
        if (k == 0 || d2 < bd2 || (d2 == bd2 && c < bidx)){ bd2 = d2; bidx = c; }
        if (k == n - 1) swin = bidx;
      }
      __syncthreads();
    }
    widx = swin;
  }

  const int t = row & (TT - 1);
  const float4 e = ((const float4*)emb)[(size_t)widx * 256 + tid];
  const float4 p = ((const float4*)pe)[(size_t)t * 256 + tid];
  float4 o;
  o.x = e.x + p.x; o.y = e.y + p.y; o.z = e.z + p.z; o.w = e.w + p.w;
  ((float4*)out)[(size_t)row * 256 + tid] = o;
}

// ---- exact fp32 fallback (no workspace needed; slow but correct) ---------
__global__ void vq_fallback(const float* __restrict__ x, const float* __restrict__ cb,
                            const float* __restrict__ emb, const float* __restrict__ pe,
                            float* __restrict__ out){
  __shared__ float4 xs[256];
  __shared__ u64 red[256];
  const int row = blockIdx.x, tid = threadIdx.x;
  xs[tid] = ((const float4*)x)[(size_t)row * 256 + tid];
  __syncthreads();
  u64 best = ~0ull;
  for (int k = tid; k < KCODES; k += 256){
    const float4* c4 = (const float4*)(cb + (size_t)k * DDIM);
    float dot = 0.f, cs = 0.f;
    for (int j = 0; j < 256; ++j){
      float4 c = c4[j], xv = xs[j];
      dot += c.x * xv.x + c.y * xv.y + c.z * xv.z + c.w * xv.w;
      cs  += c.x * c.x + c.y * c.y + c.z * c.z + c.w * c.w;
    }
    u64 p = packScore(cs - 2.f * dot, (u32)k);
    best = (p < best) ? p : best;
  }
  red[tid] = best;
  __syncthreads();
  for (int s = 128; s; s >>= 1){
    if (tid < s && red[tid + s] < red[tid]) red[tid] = red[tid + s];
    __syncthreads();
  }
  const u32 idx = (u32)(red[0] & 0xFFFFFFFFu);
  const int t = row & (TT - 1);
  const float4 e = ((const float4*)emb)[(size_t)idx * 256 + tid];
  const float4 p = ((const float4*)pe)[(size_t)t * 256 + tid];
  float4 o;
  o.x = e.x + p.x; o.y = e.y + p.y; o.z = e.z + p.z; o.w = e.w + p.w;
  ((float4*)out)[(size_t)row * 256 + tid] = o;
}

// ---- launch --------------------------------------------------------------
extern "C" void kernel_launch(void* const* d_in, const int* in_sizes, int n_in,
                              void* d_out, int out_size, void* d_ws, size_t ws_size,
                              hipStream_t stream){
  const float* x   = (const float*)d_in[0];
  const float* cb  = (const float*)d_in[1];
  const float* emb = (const float*)d_in[2];
  const float* pe  = (const float*)d_in[3];
  float* out = (float*)d_out;

  const size_t OFF_CSQ  = 0;                         // 8192 * 4 B = 32 KB
  const size_t OFF_BLK2 = 32768;                     // 8192 * 64 * 8 B = 4 MB
  const size_t OFF_AHI  = 32768 + 4194304;
  const size_t SEG      = (size_t)MROWS * DDIM * sizeof(f16);  // 16 MB
  const size_t NEEDED   = OFF_AHI + 2 * SEG;         // ~36.3 MB

  if (ws_size >= NEEDED){
    float* csq = (float*)((char*)d_ws + OFF_CSQ);
    u64* blk2 = (u64*)((char*)d_ws + OFF_BLK2);
    f16* Ahi = (f16*)((char*)d_ws + OFF_AHI);
    f16* Bhi = Ahi + (size_t)MROWS * DDIM;

    hipLaunchKernelGGL(prep_all, dim3(MROWS + KCODES), dim3(256), 0, stream,
                       x, cb, Ahi, Bhi, csq);
    hipLaunchKernelGGL(vq_gemm, dim3(32, 32), dim3(512), 0, stream, Ahi, Bhi, csq, blk2);
    hipLaunchKernelGGL(refine_gather, dim3(MROWS), dim3(256), 0, stream,
                       x, cb, emb, pe, csq, blk2, out);
  } else {
    hipLaunchKernelGGL(vq_fallback, dim3(MROWS), dim3(256), 0, stream, x, cb, emb, pe, out);
  }
}

// Round 12
// 163.501 us; speedup vs baseline: 1.1189x; 1.1189x over previous
//
#include <hip/hip_runtime.h>
#include <cstdint>
#include <cstddef>

// Problem constants (fixed by the reference)
#define BB 4
#define TT 2048
#define DDIM 1024
#define KCODES 8192
#define MROWS (BB*TT)          // 8192
// reduce margin: 0.5 (true approx-error bound, proven R8) + 2x1.0 quantization
#define MARGIN 2.5f

typedef _Float16 f16;
typedef _Float16 half8 __attribute__((ext_vector_type(8)));
typedef _Float16 half4v __attribute__((ext_vector_type(4)));
typedef float f32x4 __attribute__((ext_vector_type(4)));
typedef unsigned long long u64;
typedef unsigned int u32;

// ---- helpers -------------------------------------------------------------

// quantized packed score: scores are provably positive (~[480,1600]), so the
// raw float bits are monotone; keep top 19 bits (ulp <= 1.0) and pack the
// 13-bit col index in the low bits. min(packed) = (min score, lowest col).
__device__ __forceinline__ u32 packQ(float s, u32 col){
  return (__float_as_uint(s) & 0xFFFFE000u) | col;
}
__device__ __forceinline__ float unpackQ(u32 m){
  return __uint_as_float(m & 0xFFFFE000u);
}

// packed exact score for the fp32 fallback path
__device__ __forceinline__ u64 packScore(float s, u32 idx){
  u32 b = __float_as_uint(s);
  b ^= (b & 0x80000000u) ? 0xFFFFFFFFu : 0x80000000u;
  return ((u64)b << 32) | (u64)idx;
}

// async global->LDS, 16B per lane; lds base must be wave-uniform (HW writes lane l at +16*l)
__device__ __forceinline__ void glds16(const void* g, void* l){
  __builtin_amdgcn_global_load_lds(
      (const __attribute__((address_space(1))) unsigned int*)g,
      (__attribute__((address_space(3))) unsigned int*)l, 16, 0, 0);
}

// ---- prep: x -> Ahi (f16), cb -> Bhi (f16) + exact fp32 ||c||^2 ----------
__global__ void prep_all(const float* __restrict__ x, const float* __restrict__ cb,
                         f16* __restrict__ Ahi, f16* __restrict__ Bhi,
                         float* __restrict__ csq){
  const int row = blockIdx.x;            // 0..16383
  const int tid = threadIdx.x;
  if (row < MROWS){
    const float4 v = ((const float4*)x)[(size_t)row * 256 + tid];
    half4v hi;
    hi[0] = (f16)v.x; hi[1] = (f16)v.y; hi[2] = (f16)v.z; hi[3] = (f16)v.w;
    ((half4v*)Ahi)[(size_t)row * 256 + tid] = hi;
  } else {
    const int r = row - MROWS;
    const float4 v = ((const float4*)cb)[(size_t)r * 256 + tid];
    half4v hi;
    hi[0] = (f16)v.x; hi[1] = (f16)v.y; hi[2] = (f16)v.z; hi[3] = (f16)v.w;
    ((half4v*)Bhi)[(size_t)r * 256 + tid] = hi;
    float s = v.x*v.x + v.y*v.y + v.z*v.z + v.w*v.w;
    #pragma unroll
    for (int m = 32; m; m >>= 1) s += __shfl_xor(s, m, 64);
    __shared__ float red[4];
    if ((tid & 63) == 0) red[tid >> 6] = s;
    __syncthreads();
    if (tid == 0) csq[r] = red[0] + red[1] + red[2] + red[3];
  }
}

// ---- pass 1: approx GEMM (hi*hi, 16 K-steps) + per-block top-2 -----------
// PROVEN R10 kernel, byte-identical. 256x128 tile, BK=64, 8 waves (4m x 2n),
// SINGLE 48KB LDS buffer (3 blocks/CU), strict schedule:
// sync -> stage -> sync -> compute (no DMA/ds_read overlap — R3-R6 lesson).
// Per wave: 64x64 output acc[4][4], 6 glds16 + 16 ds_read_b128 + 32 MFMA/step.
// XOR slot swizzle both sides; T1 XCD-aware mapping (4 A-panels/XCD).
// Epilogue: quantized u32 top-2, two half-passes.
__global__ __launch_bounds__(512) void vq_gemm(
    const f16* __restrict__ Ahi, const f16* __restrict__ Bhi,
    const float* __restrict__ csq, u64* __restrict__ blk2)
{
  __shared__ f16 smem[(256 + 128) * 64];          // 48 KB
  f16* sA = smem;                                 // [256*64]
  f16* sB = smem + 256 * 64;                      // [128*64]

  const int tid  = threadIdx.x;
  const int lane = tid & 63;
  const int wid  = tid >> 6;            // 0..7
  const int wm   = wid >> 1;            // 0..3 (M quarter, 64 rows)
  const int wn   = wid & 1;             // 0..1 (N half, 64 cols)

  // T1: XCD-aware tile mapping (bijective on 32x64 grid)
  const int lin = blockIdx.y * 64 + blockIdx.x;   // 0..2047, x-fastest
  const int xcd = lin & 7;
  const int pos = lin >> 3;                       // 0..255
  const int bm  = xcd * 4 + (pos & 3);            // 4 contiguous A-panels/XCD
  const int bn  = pos >> 2;                       // 0..63, bn-major walk

  const int l15 = lane & 15, lk = lane >> 4;

  f32x4 acc[4][4];
  #pragma unroll
  for (int i = 0; i < 4; ++i)
    #pragma unroll
    for (int j = 0; j < 4; ++j)
      acc[i][j] = (f32x4)0.0f;

  // staging source geometry (pre-swizzled global column), proven R2
  const int srow = lane >> 3;                     // 0..7
  const int scol = (((lane & 7) ^ srow) * 8);     // halves, swizzled source

  for (int kt = 0; kt < 16; ++kt){
    const int kin = kt * 64;

    __syncthreads();  // previous compute done before LDS overwrite
    // A: 32 chunks of 8 rows; wave stages 4
    #pragma unroll
    for (int j = 0; j < 4; ++j){
      const int rb = (wid * 4 + j) * 8;
      glds16(Ahi + (size_t)(bm * 256 + rb + srow) * DDIM + kin + scol,
             sA + rb * 64);
    }
    // B: 16 chunks; wave stages 2
    #pragma unroll
    for (int i = 0; i < 2; ++i){
      const int rb = (wid * 2 + i) * 8;
      glds16(Bhi + (size_t)(bn * 128 + rb + srow) * DDIM + kin + scol,
             sB + rb * 64);
    }
    __syncthreads();  // staging visible (compiler drains vmcnt before s_barrier)

    #pragma unroll
    for (int kk = 0; kk < 2; ++kk){
      half8 a[4], b[4];
      #pragma unroll
      for (int mf = 0; mf < 4; ++mf){
        const int r = wm * 64 + mf * 16 + l15;
        const int p = (kk * 4 + lk) ^ (r & 7);
        a[mf] = *(const half8*)&sA[r * 64 + p * 8];
      }
      #pragma unroll
      for (int nf = 0; nf < 4; ++nf){
        const int r = wn * 64 + nf * 16 + l15;
        const int p = (kk * 4 + lk) ^ (r & 7);
        b[nf] = *(const half8*)&sB[r * 64 + p * 8];
      }
      #pragma unroll
      for (int mf = 0; mf < 4; ++mf)
        #pragma unroll
        for (int nf = 0; nf < 4; ++nf)
          acc[mf][nf] = __builtin_amdgcn_mfma_f32_16x16x32_f16(a[mf], b[nf], acc[mf][nf], 0, 0, 0);
    }
  }

  // ---- epilogue: per-(row,block) top-2 (quantized u32), two half-passes ----
  __syncthreads();                                 // loop's LDS reads done
  u32* mrg = (u32*)smem;                           // [128][68] u32 = 34816 B

  float csqv[4];
  u32 gcolv[4];
  #pragma unroll
  for (int nf = 0; nf < 4; ++nf){
    gcolv[nf] = bn * 128 + wn * 64 + nf * 16 + l15;
    csqv[nf]  = csq[gcolv[nf]];
  }
  #pragma unroll
  for (int H = 0; H < 2; ++H){
    if ((wm >> 1) == H){
      #pragma unroll
      for (int mf = 0; mf < 4; ++mf){
        #pragma unroll
        for (int r = 0; r < 4; ++r){
          const int lrow = (wm & 1) * 64 + mf * 16 + lk * 4 + r;  // 0..127 in half
          u32 b1 = 0xFFFFFFFFu, b2 = 0xFFFFFFFFu;
          #pragma unroll
          for (int nf = 0; nf < 4; ++nf){
            const u32 p = packQ(csqv[nf] - 2.0f * acc[mf][nf][r], gcolv[nf]);
            if (p < b1){ b2 = b1; b1 = p; } else if (p < b2){ b2 = p; }
          }
          *(uint2*)&mrg[lrow * 68 + (wn * 16 + l15) * 2] = make_uint2(b1, b2);
        }
      }
    }
    __syncthreads();
    if (tid < 128){
      u32 b1 = 0xFFFFFFFFu, b2 = 0xFFFFFFFFu;
      const uint4* rowp = (const uint4*)&mrg[tid * 68];
      #pragma unroll
      for (int j = 0; j < 16; ++j){
        const uint4 q = rowp[j];
        u32 vv[4] = {q.x, q.y, q.z, q.w};
        #pragma unroll
        for (int s = 0; s < 4; ++s){
          const u32 v = vv[s];
          if (v < b1){ b2 = b1; b1 = v; } else if (v < b2){ b2 = v; }
        }
      }
      blk2[(size_t)(bm * 256 + H * 128 + tid) * 64 + bn] = (u64)b1 | ((u64)b2 << 32);
    }
    __syncthreads();
  }
}

// ---- pass 2 (fused, proven R11): extraction + exact refine + gather ------
__global__ void refine_gather(const float* __restrict__ x, const float* __restrict__ cb,
                              const float* __restrict__ emb, const float* __restrict__ pe,
                              const float* __restrict__ csq,
                              const u64* __restrict__ blk2,
                              float* __restrict__ out){
  const int row = blockIdx.x, tid = threadIdx.x;
  const int wid = tid >> 6, lane = tid & 63;
  __shared__ u32 scand[8];
  __shared__ u32 scnt;
  __shared__ float red[4];
  __shared__ u32 swin;

  // wave 0: reduce 64 block-top-2s -> global min + candidates within MARGIN
  if (wid == 0){
    const u64 v = blk2[(size_t)row * 64 + lane];
    u32 c1 = (u32)v, c2 = (u32)(v >> 32);
    float thr = 0.f;
    u32 count = 0;
    for (int k = 0; k < 8; ++k){
      u32 loc = (c1 < c2) ? c1 : c2;
      #pragma unroll
      for (int m = 1; m < 64; m <<= 1){
        const u32 o = __shfl_xor(loc, m, 64);
        loc = (o < loc) ? o : loc;
      }
      const float sf = unpackQ(loc);
      if (k == 0) thr = sf + MARGIN;
      else if (sf > thr) break;
      if (lane == 0) scand[k] = loc & 0x1FFFu;
      ++count;
      if (c1 == loc) c1 = 0xFFFFFFFFu;
      if (c2 == loc) c2 = 0xFFFFFFFFu;
    }
    if (lane == 0) scnt = count;
  }
  __syncthreads();

  u32 widx = scand[0];
  const u32 n = scnt;
  if (n > 1){
    const float4 xv = ((const float4*)x)[(size_t)row * 256 + tid];
    float bd2 = 0.f; u32 bidx = 0;
    for (u32 k = 0; k < n; ++k){
      const u32 c = scand[k];
      const float4 cv = ((const float4*)cb)[(size_t)c * 256 + tid];
      float p = xv.x*cv.x + xv.y*cv.y + xv.z*cv.z + xv.w*cv.w;
      #pragma unroll
      for (int m = 32; m; m >>= 1) p += __shfl_xor(p, m, 64);
      if (lane == 0) red[wid] = p;
      __syncthreads();
      if (tid == 0){
        const float d2 = csq[c] - 2.0f * (red[0] + red[1] + red[2] + red[3]);
        if (k == 0 || d2 < bd2 || (d2 == bd2 && c < bidx)){ bd2 = d2; bidx = c; }
        if (k == n - 1) swin = bidx;
      }
      __syncthreads();
    }
    widx = swin;
  }

  const int t = row & (TT - 1);
  const float4 e = ((const float4*)emb)[(size_t)widx * 256 + tid];
  const float4 p = ((const float4*)pe)[(size_t)t * 256 + tid];
  float4 o;
  o.x = e.x + p.x; o.y = e.y + p.y; o.z = e.z + p.z; o.w = e.w + p.w;
  ((float4*)out)[(size_t)row * 256 + tid] = o;
}

// ---- exact fp32 fallback (no workspace needed; slow but correct) ---------
__global__ void vq_fallback(const float* __restrict__ x, const float* __restrict__ cb,
                            const float* __restrict__ emb, const float* __restrict__ pe,
                            float* __restrict__ out){
  __shared__ float4 xs[256];
  __shared__ u64 red[256];
  const int row = blockIdx.x, tid = threadIdx.x;
  xs[tid] = ((const float4*)x)[(size_t)row * 256 + tid];
  __syncthreads();
  u64 best = ~0ull;
  for (int k = tid; k < KCODES; k += 256){
    const float4* c4 = (const float4*)(cb + (size_t)k * DDIM);
    float dot = 0.f, cs = 0.f;
    for (int j = 0; j < 256; ++j){
      float4 c = c4[j], xv = xs[j];
      dot += c.x * xv.x + c.y * xv.y + c.z * xv.z + c.w * xv.w;
      cs  += c.x * c.x + c.y * c.y + c.z * c.z + c.w * c.w;
    }
    u64 p = packScore(cs - 2.f * dot, (u32)k);
    best = (p < best) ? p : best;
  }
  red[tid] = best;
  __syncthreads();
  for (int s = 128; s; s >>= 1){
    if (tid < s && red[tid + s] < red[tid]) red[tid] = red[tid + s];
    __syncthreads();
  }
  const u32 idx = (u32)(red[0] & 0xFFFFFFFFu);
  const int t = row & (TT - 1);
  const float4 e = ((const float4*)emb)[(size_t)idx * 256 + tid];
  const float4 p = ((const float4*)pe)[(size_t)t * 256 + tid];
  float4 o;
  o.x = e.x + p.x; o.y = e.y + p.y; o.z = e.z + p.z; o.w = e.w + p.w;
  ((float4*)out)[(size_t)row * 256 + tid] = o;
}

// ---- launch --------------------------------------------------------------
extern "C" void kernel_launch(void* const* d_in, const int* in_sizes, int n_in,
                              void* d_out, int out_size, void* d_ws, size_t ws_size,
                              hipStream_t stream){
  const float* x   = (const float*)d_in[0];
  const float* cb  = (const float*)d_in[1];
  const float* emb = (const float*)d_in[2];
  const float* pe  = (const float*)d_in[3];
  float* out = (float*)d_out;

  const size_t OFF_CSQ  = 0;                         // 8192 * 4 B = 32 KB
  const size_t OFF_BLK2 = 32768;                     // 8192 * 64 * 8 B = 4 MB
  const size_t OFF_AHI  = 32768 + 4194304;
  const size_t SEG      = (size_t)MROWS * DDIM * sizeof(f16);  // 16 MB
  const size_t NEEDED   = OFF_AHI + 2 * SEG;         // ~36.3 MB

  if (ws_size >= NEEDED){
    float* csq = (float*)((char*)d_ws + OFF_CSQ);
    u64* blk2 = (u64*)((char*)d_ws + OFF_BLK2);
    f16* Ahi = (f16*)((char*)d_ws + OFF_AHI);
    f16* Bhi = Ahi + (size_t)MROWS * DDIM;

    hipLaunchKernelGGL(prep_all, dim3(MROWS + KCODES), dim3(256), 0, stream,
                       x, cb, Ahi, Bhi, csq);
    hipLaunchKernelGGL(vq_gemm, dim3(64, 32), dim3(512), 0, stream, Ahi, Bhi, csq, blk2);
    hipLaunchKernelGGL(refine_gather, dim3(MROWS), dim3(256), 0, stream,
                       x, cb, emb, pe, csq, blk2, out);
  } else {
    hipLaunchKernelGGL(vq_fallback, dim3(MROWS), dim3(256), 0, stream, x, cb, emb, pe, out);
  }
}

// Round 13
// 153.410 us; speedup vs baseline: 1.1925x; 1.0658x over previous
//
#include <hip/hip_runtime.h>
#include <hip/hip_fp8.h>
#include <cstdint>
#include <cstddef>

// Problem constants (fixed by the reference)
#define BB 4
#define TT 2048
#define DDIM 1024
#define KCODES 8192
#define MROWS (BB*TT)          // 8192
// fp8 approx error: d2-diff sigma ~3.7 -> 10-sigma + 2.0 quantization headroom
#define MARGIN 40.0f

typedef _Float16 f16;
typedef unsigned char u8;
typedef float f32x4 __attribute__((ext_vector_type(4)));
typedef unsigned long long u64;
typedef unsigned int u32;

// ---- helpers -------------------------------------------------------------

// quantized packed score: scores are provably positive (~[480,1600]), so the
// raw float bits are monotone; keep top 19 bits (ulp <= 1.0) and pack the
// 13-bit col index in the low bits. min(packed) = (min score, lowest col).
__device__ __forceinline__ u32 packQ(float s, u32 col){
  return (__float_as_uint(s) & 0xFFFFE000u) | col;
}
__device__ __forceinline__ float unpackQ(u32 m){
  return __uint_as_float(m & 0xFFFFE000u);
}

// packed exact score for the fp32 fallback path
__device__ __forceinline__ u64 packScore(float s, u32 idx){
  u32 b = __float_as_uint(s);
  b ^= (b & 0x80000000u) ? 0xFFFFFFFFu : 0x80000000u;
  return ((u64)b << 32) | (u64)idx;
}

// async global->LDS, 16B per lane; lds base must be wave-uniform (HW writes lane l at +16*l)
__device__ __forceinline__ void glds16(const void* g, void* l){
  __builtin_amdgcn_global_load_lds(
      (const __attribute__((address_space(1))) unsigned int*)g,
      (__attribute__((address_space(3))) unsigned int*)l, 16, 0, 0);
}

// float4 -> 4 packed OCP e4m3 bytes (RNE via hip_fp8 API)
__device__ __forceinline__ u32 pack4_fp8(float4 v){
  __hip_fp8_e4m3 a(v.x), b(v.y), c(v.z), d(v.w);
  return (u32)a.__x | ((u32)b.__x << 8) | ((u32)c.__x << 16) | ((u32)d.__x << 24);
}

// ---- prep: x -> A8 (fp8), cb -> B8 (fp8) + exact fp32 ||c||^2 ------------
__global__ void prep_all(const float* __restrict__ x, const float* __restrict__ cb,
                         u8* __restrict__ A8, u8* __restrict__ B8,
                         float* __restrict__ csq){
  const int row = blockIdx.x;            // 0..16383
  const int tid = threadIdx.x;
  if (row < MROWS){
    const float4 v = ((const float4*)x)[(size_t)row * 256 + tid];
    ((u32*)A8)[(size_t)row * 256 + tid] = pack4_fp8(v);
  } else {
    const int r = row - MROWS;
    const float4 v = ((const float4*)cb)[(size_t)r * 256 + tid];
    ((u32*)B8)[(size_t)r * 256 + tid] = pack4_fp8(v);
    float s = v.x*v.x + v.y*v.y + v.z*v.z + v.w*v.w;
    #pragma unroll
    for (int m = 32; m; m >>= 1) s += __shfl_xor(s, m, 64);
    __shared__ float red[4];
    if ((tid & 63) == 0) red[tid >> 6] = s;
    __syncthreads();
    if (tid == 0) csq[r] = red[0] + red[1] + red[2] + red[3];
  }
}

// ---- pass 1: approx GEMM (fp8, 8 K-steps of BK=128) + per-block top-2 ----
// 256x128 tile, 8 waves (4m x 2n), SINGLE 48KB LDS buffer (3 blocks/CU),
// PROVEN strict schedule: sync -> stage -> sync -> compute (no DMA/ds_read
// overlap — R3-R6 lesson). Per wave-step: 6 glds16 + 32 ds_read_b64 +
// 64 MFMA fp8 (16x16x32). LDS rows = 128 B (128 fp8) = 8 x 16B slots; XOR
// slot swizzle (phys = logical ^ (row&7)) on both sides, same as f16 proven.
// ds_read_b64: lanes lk even/odd read adjacent 8B of one slot -> adjacent
// banks; rows r,r+8 share a slot 2-way (free). Epilogue identical to R12
// (C/D layout is dtype-independent).
__global__ __launch_bounds__(512) void vq_gemm(
    const u8* __restrict__ A8, const u8* __restrict__ B8,
    const float* __restrict__ csq, u64* __restrict__ blk2)
{
  __shared__ u8 smem[(256 + 128) * 128];          // 48 KB
  u8* sA = smem;                                  // [256 rows][128 B]
  u8* sB = smem + 256 * 128;                      // [128 rows][128 B]

  const int tid  = threadIdx.x;
  const int lane = tid & 63;
  const int wid  = tid >> 6;            // 0..7
  const int wm   = wid >> 1;            // 0..3 (M quarter, 64 rows)
  const int wn   = wid & 1;             // 0..1 (N half, 64 cols)

  // T1: XCD-aware tile mapping (bijective on 32x64 grid)
  const int lin = blockIdx.y * 64 + blockIdx.x;   // 0..2047, x-fastest
  const int xcd = lin & 7;
  const int pos = lin >> 3;                       // 0..255
  const int bm  = xcd * 4 + (pos & 3);            // 4 contiguous A-panels/XCD
  const int bn  = pos >> 2;                       // 0..63, bn-major walk

  const int l15 = lane & 15, lk = lane >> 4;

  f32x4 acc[4][4];
  #pragma unroll
  for (int i = 0; i < 4; ++i)
    #pragma unroll
    for (int j = 0; j < 4; ++j)
      acc[i][j] = (f32x4)0.0f;

  // staging source geometry (pre-swizzled global 16B slot), proven involution
  const int srow = lane >> 3;                     // 0..7 within an 8-row chunk
  const int sslot = (lane & 7) ^ srow;            // swizzled source slot

  for (int kt = 0; kt < 8; ++kt){
    const int kin = kt * 128;                     // byte (=elem) offset in row

    __syncthreads();  // previous compute done before LDS overwrite
    // A: 32 chunks of 8 rows x 128B; wave stages 4
    #pragma unroll
    for (int j = 0; j < 4; ++j){
      const int rb = (wid * 4 + j) * 8;
      glds16(A8 + (size_t)(bm * 256 + rb + srow) * DDIM + kin + sslot * 16,
             sA + rb * 128);
    }
    // B: 16 chunks; wave stages 2
    #pragma unroll
    for (int i = 0; i < 2; ++i){
      const int rb = (wid * 2 + i) * 8;
      glds16(B8 + (size_t)(bn * 128 + rb + srow) * DDIM + kin + sslot * 16,
             sB + rb * 128);
    }
    __syncthreads();  // staging visible (compiler drains vmcnt before s_barrier)

    // 4 MFMA k-instances of 32 within the 128-K tile
    #pragma unroll
    for (int kk = 0; kk < 4; ++kk){
      long a[4], b[4];
      #pragma unroll
      for (int mf = 0; mf < 4; ++mf){
        const int r = wm * 64 + mf * 16 + l15;
        const int p = (kk * 2 + (lk >> 1)) ^ (r & 7);   // swizzled 16B slot
        a[mf] = *(const long*)&sA[r * 128 + p * 16 + (lk & 1) * 8];
      }
      #pragma unroll
      for (int nf = 0; nf < 4; ++nf){
        const int r = wn * 64 + nf * 16 + l15;
        const int p = (kk * 2 + (lk >> 1)) ^ (r & 7);
        b[nf] = *(const long*)&sB[r * 128 + p * 16 + (lk & 1) * 8];
      }
      #pragma unroll
      for (int mf = 0; mf < 4; ++mf)
        #pragma unroll
        for (int nf = 0; nf < 4; ++nf)
          acc[mf][nf] = __builtin_amdgcn_mfma_f32_16x16x32_fp8_fp8(a[mf], b[nf], acc[mf][nf], 0, 0, 0);
    }
  }

  // ---- epilogue: per-(row,block) top-2 (quantized u32), two half-passes ----
  // byte-identical logic to R12 (acc layout is dtype-independent)
  __syncthreads();                                 // loop's LDS reads done
  u32* mrg = (u32*)smem;                           // [128][68] u32 = 34816 B

  float csqv[4];
  u32 gcolv[4];
  #pragma unroll
  for (int nf = 0; nf < 4; ++nf){
    gcolv[nf] = bn * 128 + wn * 64 + nf * 16 + l15;
    csqv[nf]  = csq[gcolv[nf]];
  }
  #pragma unroll
  for (int H = 0; H < 2; ++H){
    if ((wm >> 1) == H){
      #pragma unroll
      for (int mf = 0; mf < 4; ++mf){
        #pragma unroll
        for (int r = 0; r < 4; ++r){
          const int lrow = (wm & 1) * 64 + mf * 16 + lk * 4 + r;  // 0..127 in half
          u32 b1 = 0xFFFFFFFFu, b2 = 0xFFFFFFFFu;
          #pragma unroll
          for (int nf = 0; nf < 4; ++nf){
            const u32 p = packQ(csqv[nf] - 2.0f * acc[mf][nf][r], gcolv[nf]);
            if (p < b1){ b2 = b1; b1 = p; } else if (p < b2){ b2 = p; }
          }
          *(uint2*)&mrg[lrow * 68 + (wn * 16 + l15) * 2] = make_uint2(b1, b2);
        }
      }
    }
    __syncthreads();
    if (tid < 128){
      u32 b1 = 0xFFFFFFFFu, b2 = 0xFFFFFFFFu;
      const uint4* rowp = (const uint4*)&mrg[tid * 68];
      #pragma unroll
      for (int j = 0; j < 16; ++j){
        const uint4 q = rowp[j];
        u32 vv[4] = {q.x, q.y, q.z, q.w};
        #pragma unroll
        for (int s = 0; s < 4; ++s){
          const u32 v = vv[s];
          if (v < b1){ b2 = b1; b1 = v; } else if (v < b2){ b2 = v; }
        }
      }
      blk2[(size_t)(bm * 256 + H * 128 + tid) * 64 + bn] = (u64)b1 | ((u64)b2 << 32);
    }
    __syncthreads();
  }
}

// ---- pass 2 (fused, proven R11/R12): extraction + exact refine + gather --
__global__ void refine_gather(const float* __restrict__ x, const float* __restrict__ cb,
                              const float* __restrict__ emb, const float* __restrict__ pe,
                              const float* __restrict__ csq,
                              const u64* __restrict__ blk2,
                              float* __restrict__ out){
  const int row = blockIdx.x, tid = threadIdx.x;
  const int wid = tid >> 6, lane = tid & 63;
  __shared__ u32 scand[8];
  __shared__ u32 scnt;
  __shared__ float red[4];
  __shared__ u32 swin;

  // wave 0: reduce 64 block-top-2s -> global min + candidates within MARGIN
  // (ascending extraction: the 8 approx-nearest always include the winner)
  if (wid == 0){
    const u64 v = blk2[(size_t)row * 64 + lane];
    u32 c1 = (u32)v, c2 = (u32)(v >> 32);
    float thr = 0.f;
    u32 count = 0;
    for (int k = 0; k < 8; ++k){
      u32 loc = (c1 < c2) ? c1 : c2;
      #pragma unroll
      for (int m = 1; m < 64; m <<= 1){
        const u32 o = __shfl_xor(loc, m, 64);
        loc = (o < loc) ? o : loc;
      }
      const float sf = unpackQ(loc);
      if (k == 0) thr = sf + MARGIN;
      else if (sf > thr) break;
      if (lane == 0) scand[k] = loc & 0x1FFFu;
      ++count;
      if (c1 == loc) c1 = 0xFFFFFFFFu;
      if (c2 == loc) c2 = 0xFFFFFFFFu;
    }
    if (lane == 0) scnt = count;
  }
  __syncthreads();

  u32 widx = scand[0];
  const u32 n = scnt;
  if (n > 1){
    const float4 xv = ((const float4*)x)[(size_t)row * 256 + tid];
    float bd2 = 0.f; u32 bidx = 0;
    for (u32 k = 0; k < n; ++k){
      const u32 c = scand[k];
      const float4 cv = ((const float4*)cb)[(size_t)c * 256 + tid];
      float p = xv.x*cv.x + xv.y*cv.y + xv.z*cv.z + xv.w*cv.w;
      #pragma unroll
      for (int m = 32; m; m >>= 1) p += __shfl_xor(p, m, 64);
      if (lane == 0) red[wid] = p;
      __syncthreads();
      if (tid == 0){
        const float d2 = csq[c] - 2.0f * (red[0] + red[1] + red[2] + red[3]);
        if (k == 0 || d2 < bd2 || (d2 == bd2 && c < bidx)){ bd2 = d2; bidx = c; }
        if (k == n - 1) swin = bidx;
      }
      __syncthreads();
    }
    widx = swin;
  }

  const int t = row & (TT - 1);
  const float4 e = ((const float4*)emb)[(size_t)widx * 256 + tid];
  const float4 p = ((const float4*)pe)[(size_t)t * 256 + tid];
  float4 o;
  o.x = e.x + p.x; o.y = e.y + p.y; o.z = e.z + p.z; o.w = e.w + p.w;
  ((float4*)out)[(size_t)row * 256 + tid] = o;
}

// ---- exact fp32 fallback (no workspace needed; slow but correct) ---------
__global__ void vq_fallback(const float* __restrict__ x, const float* __restrict__ cb,
                            const float* __restrict__ emb, const float* __restrict__ pe,
                            float* __restrict__ out){
  __shared__ float4 xs[256];
  __shared__ u64 red[256];
  const int row = blockIdx.x, tid = threadIdx.x;
  xs[tid] = ((const float4*)x)[(size_t)row * 256 + tid];
  __syncthreads();
  u64 best = ~0ull;
  for (int k = tid; k < KCODES; k += 256){
    const float4* c4 = (const float4*)(cb + (size_t)k * DDIM);
    float dot = 0.f, cs = 0.f;
    for (int j = 0; j < 256; ++j){
      float4 c = c4[j], xv = xs[j];
      dot += c.x * xv.x + c.y * xv.y + c.z * xv.z + c.w * xv.w;
      cs  += c.x * c.x + c.y * c.y + c.z * c.z + c.w * c.w;
    }
    u64 p = packScore(cs - 2.f * dot, (u32)k);
    best = (p < best) ? p : best;
  }
  red[tid] = best;
  __syncthreads();
  for (int s = 128; s; s >>= 1){
    if (tid < s && red[tid + s] < red[tid]) red[tid] = red[tid + s];
    __syncthreads();
  }
  const u32 idx = (u32)(red[0] & 0xFFFFFFFFu);
  const int t = row & (TT - 1);
  const float4 e = ((const float4*)emb)[(size_t)idx * 256 + tid];
  const float4 p = ((const float4*)pe)[(size_t)t * 256 + tid];
  float4 o;
  o.x = e.x + p.x; o.y = e.y + p.y; o.z = e.z + p.z; o.w = e.w + p.w;
  ((float4*)out)[(size_t)row * 256 + tid] = o;
}

// ---- launch --------------------------------------------------------------
extern "C" void kernel_launch(void* const* d_in, const int* in_sizes, int n_in,
                              void* d_out, int out_size, void* d_ws, size_t ws_size,
                              hipStream_t stream){
  const float* x   = (const float*)d_in[0];
  const float* cb  = (const float*)d_in[1];
  const float* emb = (const float*)d_in[2];
  const float* pe  = (const float*)d_in[3];
  float* out = (float*)d_out;

  const size_t OFF_CSQ  = 0;                         // 8192 * 4 B = 32 KB
  const size_t OFF_BLK2 = 32768;                     // 8192 * 64 * 8 B = 4 MB
  const size_t OFF_A8   = 32768 + 4194304;
  const size_t SEG      = (size_t)MROWS * DDIM;      // 8 MB (fp8)
  const size_t NEEDED   = OFF_A8 + 2 * SEG;          // ~20.3 MB

  if (ws_size >= NEEDED){
    float* csq = (float*)((char*)d_ws + OFF_CSQ);
    u64* blk2 = (u64*)((char*)d_ws + OFF_BLK2);
    u8* A8 = (u8*)((char*)d_ws + OFF_A8);
    u8* B8 = A8 + SEG;

    hipLaunchKernelGGL(prep_all, dim3(MROWS + KCODES), dim3(256), 0, stream,
                       x, cb, A8, B8, csq);
    hipLaunchKernelGGL(vq_gemm, dim3(64, 32), dim3(512), 0, stream, A8, B8, csq, blk2);
    hipLaunchKernelGGL(refine_gather, dim3(MROWS), dim3(256), 0, stream,
                       x, cb, emb, pe, csq, blk2, out);
  } else {
    hipLaunchKernelGGL(vq_fallback, dim3(MROWS), dim3(256), 0, stream, x, cb, emb, pe, out);
  }
}

// Round 14
// 147.536 us; speedup vs baseline: 1.2399x; 1.0398x over previous
//
#include <hip/hip_runtime.h>
#include <hip/hip_fp8.h>
#include <cstdint>
#include <cstddef>

// Problem constants (fixed by the reference)
#define BB 4
#define TT 2048
#define DDIM 1024
#define KCODES 8192
#define MROWS (BB*TT)          // 8192
// fp8 approx error: d2-diff sigma ~3.7 -> 10-sigma + 2.0 quantization headroom
#define MARGIN 40.0f

typedef _Float16 f16;
typedef unsigned char u8;
typedef float f32x4 __attribute__((ext_vector_type(4)));
typedef unsigned long long u64;
typedef unsigned int u32;

// ---- helpers -------------------------------------------------------------

// quantized packed score: scores are provably positive (~[480,1600]), so the
// raw float bits are monotone; keep top 19 bits (ulp <= 1.0) and pack the
// 13-bit col index in the low bits. min(packed) = (min score, lowest col).
__device__ __forceinline__ u32 packQ(float s, u32 col){
  return (__float_as_uint(s) & 0xFFFFE000u) | col;
}
__device__ __forceinline__ float unpackQ(u32 m){
  return __uint_as_float(m & 0xFFFFE000u);
}

// packed exact score for the fp32 fallback path
__device__ __forceinline__ u64 packScore(float s, u32 idx){
  u32 b = __float_as_uint(s);
  b ^= (b & 0x80000000u) ? 0xFFFFFFFFu : 0x80000000u;
  return ((u64)b << 32) | (u64)idx;
}

// async global->LDS, 16B per lane; lds base must be wave-uniform (HW writes lane l at +16*l)
__device__ __forceinline__ void glds16(const void* g, void* l){
  __builtin_amdgcn_global_load_lds(
      (const __attribute__((address_space(1))) unsigned int*)g,
      (__attribute__((address_space(3))) unsigned int*)l, 16, 0, 0);
}

// float4 -> 4 packed OCP e4m3 bytes (RNE via hip_fp8 API)
__device__ __forceinline__ u32 pack4_fp8(float4 v){
  __hip_fp8_e4m3 a(v.x), b(v.y), c(v.z), d(v.w);
  return (u32)a.__x | ((u32)b.__x << 8) | ((u32)c.__x << 16) | ((u32)d.__x << 24);
}

// ---- prep: x -> A8 (fp8), cb -> B8 (fp8) + exact fp32 ||c||^2 ------------
// K-PERMUTED layout (R14): within each row, the 8B half-index (byte bit 3) is
// XORed with bit 3 of the row. The dot product is invariant (same permutation
// on A and B); the matching read-side XOR makes the b64 LDS reads cover all
// 32 banks per 16-lane phase (kills R13's 1.7e7 bank conflicts).
__global__ void prep_all(const float* __restrict__ x, const float* __restrict__ cb,
                         u8* __restrict__ A8, u8* __restrict__ B8,
                         float* __restrict__ csq){
  const int row = blockIdx.x;            // 0..16383
  const int tid = threadIdx.x;
  if (row < MROWS){
    const int r8 = (row >> 3) & 1;
    const float4 v = ((const float4*)x)[(size_t)row * 256 + tid];
    ((u32*)A8)[(size_t)row * 256 + (tid ^ (r8 << 1))] = pack4_fp8(v);
  } else {
    const int r = row - MROWS;
    const int r8 = (r >> 3) & 1;
    const float4 v = ((const float4*)cb)[(size_t)r * 256 + tid];
    ((u32*)B8)[(size_t)r * 256 + (tid ^ (r8 << 1))] = pack4_fp8(v);
    float s = v.x*v.x + v.y*v.y + v.z*v.z + v.w*v.w;
    #pragma unroll
    for (int m = 32; m; m >>= 1) s += __shfl_xor(s, m, 64);
    __shared__ float red[4];
    if ((tid & 63) == 0) red[tid >> 6] = s;
    __syncthreads();
    if (tid == 0) csq[r] = red[0] + red[1] + red[2] + red[3];
  }
}

// ---- pass 1: approx GEMM (fp8, 8 K-steps of BK=128) + per-block top-2 ----
// 256x128 tile, 8 waves (4m x 2n), SINGLE 48KB LDS buffer (3 blocks/CU),
// PROVEN strict schedule: sync -> stage -> sync -> compute (no DMA/ds_read
// overlap — R3-R6 lesson). Per wave-step: 6 glds16 + 32 ds_read_b64 +
// 64 MFMA fp8 (16x16x32). XOR slot swizzle (phys = logical ^ (row&7)) on
// both sides (proven) + R14 half-bit permutation: read half =
// (lk&1) ^ (l15>>3), matching prep's layout -> conflict-free b64 reads.
// Epilogue identical to R12/R13 (C/D layout is dtype-independent).
__global__ __launch_bounds__(512) void vq_gemm(
    const u8* __restrict__ A8, const u8* __restrict__ B8,
    const float* __restrict__ csq, u64* __restrict__ blk2)
{
  __shared__ u8 smem[(256 + 128) * 128];          // 48 KB
  u8* sA = smem;                                  // [256 rows][128 B]
  u8* sB = smem + 256 * 128;                      // [128 rows][128 B]

  const int tid  = threadIdx.x;
  const int lane = tid & 63;
  const int wid  = tid >> 6;            // 0..7
  const int wm   = wid >> 1;            // 0..3 (M quarter, 64 rows)
  const int wn   = wid & 1;             // 0..1 (N half, 64 cols)

  // T1: XCD-aware tile mapping (bijective on 32x64 grid)
  const int lin = blockIdx.y * 64 + blockIdx.x;   // 0..2047, x-fastest
  const int xcd = lin & 7;
  const int pos = lin >> 3;                       // 0..255
  const int bm  = xcd * 4 + (pos & 3);            // 4 contiguous A-panels/XCD
  const int bn  = pos >> 2;                       // 0..63, bn-major walk

  const int l15 = lane & 15, lk = lane >> 4;

  f32x4 acc[4][4];
  #pragma unroll
  for (int i = 0; i < 4; ++i)
    #pragma unroll
    for (int j = 0; j < 4; ++j)
      acc[i][j] = (f32x4)0.0f;

  // staging source geometry (pre-swizzled global 16B slot), proven involution
  const int srow = lane >> 3;                     // 0..7 within an 8-row chunk
  const int sslot = (lane & 7) ^ srow;            // swizzled source slot

  // read-side half-bit (R14): matches prep's (row>>3)&1 permutation,
  // since bit 3 of the fragment row equals l15>>3 for both A and B.
  const int rdhalfA = l15 >> 3;

  for (int kt = 0; kt < 8; ++kt){
    const int kin = kt * 128;                     // byte (=elem) offset in row

    __syncthreads();  // previous compute done before LDS overwrite
    // A: 32 chunks of 8 rows x 128B; wave stages 4
    #pragma unroll
    for (int j = 0; j < 4; ++j){
      const int rb = (wid * 4 + j) * 8;
      glds16(A8 + (size_t)(bm * 256 + rb + srow) * DDIM + kin + sslot * 16,
             sA + rb * 128);
    }
    // B: 16 chunks; wave stages 2
    #pragma unroll
    for (int i = 0; i < 2; ++i){
      const int rb = (wid * 2 + i) * 8;
      glds16(B8 + (size_t)(bn * 128 + rb + srow) * DDIM + kin + sslot * 16,
             sB + rb * 128);
    }
    __syncthreads();  // staging visible (compiler drains vmcnt before s_barrier)

    // 4 MFMA k-instances of 32 within the 128-K tile
    #pragma unroll
    for (int kk = 0; kk < 4; ++kk){
      long a[4], b[4];
      const int hb = ((lk & 1) ^ rdhalfA) * 8;    // permuted half byte offset
      #pragma unroll
      for (int mf = 0; mf < 4; ++mf){
        const int r = wm * 64 + mf * 16 + l15;
        const int p = (kk * 2 + (lk >> 1)) ^ (r & 7);   // swizzled 16B slot
        a[mf] = *(const long*)&sA[r * 128 + p * 16 + hb];
      }
      #pragma unroll
      for (int nf = 0; nf < 4; ++nf){
        const int r = wn * 64 + nf * 16 + l15;
        const int p = (kk * 2 + (lk >> 1)) ^ (r & 7);
        b[nf] = *(const long*)&sB[r * 128 + p * 16 + hb];
      }
      #pragma unroll
      for (int mf = 0; mf < 4; ++mf)
        #pragma unroll
        for (int nf = 0; nf < 4; ++nf)
          acc[mf][nf] = __builtin_amdgcn_mfma_f32_16x16x32_fp8_fp8(a[mf], b[nf], acc[mf][nf], 0, 0, 0);
    }
  }

  // ---- epilogue: per-(row,block) top-2 (quantized u32), two half-passes ----
  // byte-identical logic to R12/R13 (acc layout is dtype-independent)
  __syncthreads();                                 // loop's LDS reads done
  u32* mrg = (u32*)smem;                           // [128][68] u32 = 34816 B

  float csqv[4];
  u32 gcolv[4];
  #pragma unroll
  for (int nf = 0; nf < 4; ++nf){
    gcolv[nf] = bn * 128 + wn * 64 + nf * 16 + l15;
    csqv[nf]  = csq[gcolv[nf]];
  }
  #pragma unroll
  for (int H = 0; H < 2; ++H){
    if ((wm >> 1) == H){
      #pragma unroll
      for (int mf = 0; mf < 4; ++mf){
        #pragma unroll
        for (int r = 0; r < 4; ++r){
          const int lrow = (wm & 1) * 64 + mf * 16 + lk * 4 + r;  // 0..127 in half
          u32 b1 = 0xFFFFFFFFu, b2 = 0xFFFFFFFFu;
          #pragma unroll
          for (int nf = 0; nf < 4; ++nf){
            const u32 p = packQ(csqv[nf] - 2.0f * acc[mf][nf][r], gcolv[nf]);
            if (p < b1){ b2 = b1; b1 = p; } else if (p < b2){ b2 = p; }
          }
          *(uint2*)&mrg[lrow * 68 + (wn * 16 + l15) * 2] = make_uint2(b1, b2);
        }
      }
    }
    __syncthreads();
    if (tid < 128){
      u32 b1 = 0xFFFFFFFFu, b2 = 0xFFFFFFFFu;
      const uint4* rowp = (const uint4*)&mrg[tid * 68];
      #pragma unroll
      for (int j = 0; j < 16; ++j){
        const uint4 q = rowp[j];
        u32 vv[4] = {q.x, q.y, q.z, q.w};
        #pragma unroll
        for (int s = 0; s < 4; ++s){
          const u32 v = vv[s];
          if (v < b1){ b2 = b1; b1 = v; } else if (v < b2){ b2 = v; }
        }
      }
      blk2[(size_t)(bm * 256 + H * 128 + tid) * 64 + bn] = (u64)b1 | ((u64)b2 << 32);
    }
    __syncthreads();
  }
}

// ---- pass 2 (fused, proven R11/R12): extraction + exact refine + gather --
__global__ void refine_gather(const float* __restrict__ x, const float* __restrict__ cb,
                              const float* __restrict__ emb, const float* __restrict__ pe,
                              const float* __restrict__ csq,
                              const u64* __restrict__ blk2,
                              float* __restrict__ out){
  const int row = blockIdx.x, tid = threadIdx.x;
  const int wid = tid >> 6, lane = tid & 63;
  __shared__ u32 scand[8];
  __shared__ u32 scnt;
  __shared__ float red[4];
  __shared__ u32 swin;

  // wave 0: reduce 64 block-top-2s -> global min + candidates within MARGIN
  // (ascending extraction: the 8 approx-nearest always include the winner)
  if (wid == 0){
    const u64 v = blk2[(size_t)row * 64 + lane];
    u32 c1 = (u32)v, c2 = (u32)(v >> 32);
    float thr = 0.f;
    u32 count = 0;
    for (int k = 0; k < 8; ++k){
      u32 loc = (c1 < c2) ? c1 : c2;
      #pragma unroll
      for (int m = 1; m < 64; m <<= 1){
        const u32 o = __shfl_xor(loc, m, 64);
        loc = (o < loc) ? o : loc;
      }
      const float sf = unpackQ(loc);
      if (k == 0) thr = sf + MARGIN;
      else if (sf > thr) break;
      if (lane == 0) scand[k] = loc & 0x1FFFu;
      ++count;
      if (c1 == loc) c1 = 0xFFFFFFFFu;
      if (c2 == loc) c2 = 0xFFFFFFFFu;
    }
    if (lane == 0) scnt = count;
  }
  __syncthreads();

  u32 widx = scand[0];
  const u32 n = scnt;
  if (n > 1){
    const float4 xv = ((const float4*)x)[(size_t)row * 256 + tid];
    float bd2 = 0.f; u32 bidx = 0;
    for (u32 k = 0; k < n; ++k){
      const u32 c = scand[k];
      const float4 cv = ((const float4*)cb)[(size_t)c * 256 + tid];
      float p = xv.x*cv.x + xv.y*cv.y + xv.z*cv.z + xv.w*cv.w;
      #pragma unroll
      for (int m = 32; m; m >>= 1) p += __shfl_xor(p, m, 64);
      if (lane == 0) red[wid] = p;
      __syncthreads();
      if (tid == 0){
        const float d2 = csq[c] - 2.0f * (red[0] + red[1] + red[2] + red[3]);
        if (k == 0 || d2 < bd2 || (d2 == bd2 && c < bidx)){ bd2 = d2; bidx = c; }
        if (k == n - 1) swin = bidx;
      }
      __syncthreads();
    }
    widx = swin;
  }

  const int t = row & (TT - 1);
  const float4 e = ((const float4*)emb)[(size_t)widx * 256 + tid];
  const float4 p = ((const float4*)pe)[(size_t)t * 256 + tid];
  float4 o;
  o.x = e.x + p.x; o.y = e.y + p.y; o.z = e.z + p.z; o.w = e.w + p.w;
  ((float4*)out)[(size_t)row * 256 + tid] = o;
}

// ---- exact fp32 fallback (no workspace needed; slow but correct) ---------
__global__ void vq_fallback(const float* __restrict__ x, const float* __restrict__ cb,
                            const float* __restrict__ emb, const float* __restrict__ pe,
                            float* __restrict__ out){
  __shared__ float4 xs[256];
  __shared__ u64 red[256];
  const int row = blockIdx.x, tid = threadIdx.x;
  xs[tid] = ((const float4*)x)[(size_t)row * 256 + tid];
  __syncthreads();
  u64 best = ~0ull;
  for (int k = tid; k < KCODES; k += 256){
    const float4* c4 = (const float4*)(cb + (size_t)k * DDIM);
    float dot = 0.f, cs = 0.f;
    for (int j = 0; j < 256; ++j){
      float4 c = c4[j], xv = xs[j];
      dot += c.x * xv.x + c.y * xv.y + c.z * xv.z + c.w * xv.w;
      cs  += c.x * c.x + c.y * c.y + c.z * c.z + c.w * c.w;
    }
    u64 p = packScore(cs - 2.f * dot, (u32)k);
    best = (p < best) ? p : best;
  }
  red[tid] = best;
  __syncthreads();
  for (int s = 128; s; s >>= 1){
    if (tid < s && red[tid + s] < red[tid]) red[tid] = red[tid + s];
    __syncthreads();
  }
  const u32 idx = (u32)(red[0] & 0xFFFFFFFFu);
  const int t = row & (TT - 1);
  const float4 e = ((const float4*)emb)[(size_t)idx * 256 + tid];
  const float4 p = ((const float4*)pe)[(size_t)t * 256 + tid];
  float4 o;
  o.x = e.x + p.x; o.y = e.y + p.y; o.z = e.z + p.z; o.w = e.w + p.w;
  ((float4*)out)[(size_t)row * 256 + tid] = o;
}

// ---- launch --------------------------------------------------------------
extern "C" void kernel_launch(void* const* d_in, const int* in_sizes, int n_in,
                              void* d_out, int out_size, void* d_ws, size_t ws_size,
                              hipStream_t stream){
  const float* x   = (const float*)d_in[0];
  const float* cb  = (const float*)d_in[1];
  const float* emb = (const float*)d_in[2];
  const float* pe  = (const float*)d_in[3];
  float* out = (float*)d_out;

  const size_t OFF_CSQ  = 0;                         // 8192 * 4 B = 32 KB
  const size_t OFF_BLK2 = 32768;                     // 8192 * 64 * 8 B = 4 MB
  const size_t OFF_A8   = 32768 + 4194304;
  const size_t SEG      = (size_t)MROWS * DDIM;      // 8 MB (fp8)
  const size_t NEEDED   = OFF_A8 + 2 * SEG;          // ~20.3 MB

  if (ws_size >= NEEDED){
    float* csq = (float*)((char*)d_ws + OFF_CSQ);
    u64* blk2 = (u64*)((char*)d_ws + OFF_BLK2);
    u8* A8 = (u8*)((char*)d_ws + OFF_A8);
    u8* B8 = A8 + SEG;

    hipLaunchKernelGGL(prep_all, dim3(MROWS + KCODES), dim3(256), 0, stream,
                       x, cb, A8, B8, csq);
    hipLaunchKernelGGL(vq_gemm, dim3(64, 32), dim3(512), 0, stream, A8, B8, csq, blk2);
    hipLaunchKernelGGL(refine_gather, dim3(MROWS), dim3(256), 0, stream,
                       x, cb, emb, pe, csq, blk2, out);
  } else {
    hipLaunchKernelGGL(vq_fallback, dim3(MROWS), dim3(256), 0, stream, x, cb, emb, pe, out);
  }
}

// Round 15
// 115.456 us; speedup vs baseline: 1.5845x; 1.2779x over previous
//
#include <hip/hip_runtime.h>
#include <cstdint>
#include <cstddef>

// Problem constants (fixed by the reference)
#define BB 4
#define TT 2048
#define DDIM 1024
#define KCODES 8192
#define MROWS (BB*TT)          // 8192
// i8 approx error: d2-diff sigma ~2.1 -> ~10 sigma + packQ quantization headroom
#define MARGIN 24.0f
// i8 quantization scale: clip at ~7 sigma (P(clip) ~1e-5 over all elements)
#define QSCALE 18.0f
#define TWO_INV_S2 (2.0f / (QSCALE * QSCALE))

typedef unsigned char u8;
typedef float f32x4 __attribute__((ext_vector_type(4)));
typedef int i32x4 __attribute__((ext_vector_type(4)));
typedef unsigned long long u64;
typedef unsigned int u32;

// ---- helpers -------------------------------------------------------------

// quantized packed score: scores are provably positive (~[480,1600]), so the
// raw float bits are monotone; keep top 19 bits (ulp <= ~1.5) and pack the
// 13-bit col index in the low bits. min(packed) = (min score, lowest col).
__device__ __forceinline__ u32 packQ(float s, u32 col){
  return (__float_as_uint(s) & 0xFFFFE000u) | col;
}
__device__ __forceinline__ float unpackQ(u32 m){
  return __uint_as_float(m & 0xFFFFE000u);
}

// packed exact score for the fp32 fallback path
__device__ __forceinline__ u64 packScore(float s, u32 idx){
  u32 b = __float_as_uint(s);
  b ^= (b & 0x80000000u) ? 0xFFFFFFFFu : 0x80000000u;
  return ((u64)b << 32) | (u64)idx;
}

// async global->LDS, 16B per lane; lds base must be wave-uniform (HW writes lane l at +16*l)
__device__ __forceinline__ void glds16(const void* g, void* l){
  __builtin_amdgcn_global_load_lds(
      (const __attribute__((address_space(1))) unsigned int*)g,
      (__attribute__((address_space(3))) unsigned int*)l, 16, 0, 0);
}

// float4 -> 4 packed symmetric int8 (RNE, clamp +-127)
__device__ __forceinline__ u32 pack4_i8(float4 v){
  int a = __float2int_rn(v.x * QSCALE); a = a < -127 ? -127 : (a > 127 ? 127 : a);
  int b = __float2int_rn(v.y * QSCALE); b = b < -127 ? -127 : (b > 127 ? 127 : b);
  int c = __float2int_rn(v.z * QSCALE); c = c < -127 ? -127 : (c > 127 ? 127 : c);
  int d = __float2int_rn(v.w * QSCALE); d = d < -127 ? -127 : (d > 127 ? 127 : d);
  return ((u32)(u8)a) | (((u32)(u8)b) << 8) | (((u32)(u8)c) << 16) | (((u32)(u8)d) << 24);
}

// ---- prep: x -> A8 (i8), cb -> B8 (i8) + exact fp32 ||c||^2 --------------
// Plain linear layout (the b128 read path needs no K-permutation).
__global__ void prep_all(const float* __restrict__ x, const float* __restrict__ cb,
                         u8* __restrict__ A8, u8* __restrict__ B8,
                         float* __restrict__ csq){
  const int row = blockIdx.x;            // 0..16383
  const int tid = threadIdx.x;
  if (row < MROWS){
    const float4 v = ((const float4*)x)[(size_t)row * 256 + tid];
    ((u32*)A8)[(size_t)row * 256 + tid] = pack4_i8(v);
  } else {
    const int r = row - MROWS;
    const float4 v = ((const float4*)cb)[(size_t)r * 256 + tid];
    ((u32*)B8)[(size_t)r * 256 + tid] = pack4_i8(v);
    float s = v.x*v.x + v.y*v.y + v.z*v.z + v.w*v.w;
    #pragma unroll
    for (int m = 32; m; m >>= 1) s += __shfl_xor(s, m, 64);
    __shared__ float red[4];
    if ((tid & 63) == 0) red[tid >> 6] = s;
    __syncthreads();
    if (tid == 0) csq[r] = red[0] + red[1] + red[2] + red[3];
  }
}

// ---- pass 1: approx GEMM (i8, 8 K-steps of BK=128) + per-block top-2 -----
// 256x128 tile, 8 waves (4m x 2n), SINGLE 48KB LDS buffer (3 blocks/CU),
// PROVEN strict schedule: sync -> stage -> sync -> compute (no DMA/ds_read
// overlap — R3-R6 lesson). Per wave-step: 6 glds16 + 16 ds_read_b128 +
// 32 MFMA i8 (16x16x64, 2x the fp8 rate). LDS rows = 128 B = 8 x 16B slots;
// XOR slot swizzle (phys = logical ^ (row&7)) on both sides — the EXACT
// R2-proven conflict-free b128 geometry (lane reads 16B at slot kk*4+lk).
// Epilogue: int32 acc -> float score via TWO_INV_S2; layout unchanged
// (C/D mapping is dtype-independent).
__global__ __launch_bounds__(512) void vq_gemm(
    const u8* __restrict__ A8, const u8* __restrict__ B8,
    const float* __restrict__ csq, u64* __restrict__ blk2)
{
  __shared__ u8 smem[(256 + 128) * 128];          // 48 KB
  u8* sA = smem;                                  // [256 rows][128 B]
  u8* sB = smem + 256 * 128;                      // [128 rows][128 B]

  const int tid  = threadIdx.x;
  const int lane = tid & 63;
  const int wid  = tid >> 6;            // 0..7
  const int wm   = wid >> 1;            // 0..3 (M quarter, 64 rows)
  const int wn   = wid & 1;             // 0..1 (N half, 64 cols)

  // T1: XCD-aware tile mapping (bijective on 32x64 grid)
  const int lin = blockIdx.y * 64 + blockIdx.x;   // 0..2047, x-fastest
  const int xcd = lin & 7;
  const int pos = lin >> 3;                       // 0..255
  const int bm  = xcd * 4 + (pos & 3);            // 4 contiguous A-panels/XCD
  const int bn  = pos >> 2;                       // 0..63, bn-major walk

  const int l15 = lane & 15, lk = lane >> 4;

  i32x4 acc[4][4];
  #pragma unroll
  for (int i = 0; i < 4; ++i)
    #pragma unroll
    for (int j = 0; j < 4; ++j)
      acc[i][j] = (i32x4)0;

  // staging source geometry (pre-swizzled global 16B slot), proven involution
  const int srow = lane >> 3;                     // 0..7 within an 8-row chunk
  const int sslot = (lane & 7) ^ srow;            // swizzled source slot

  for (int kt = 0; kt < 8; ++kt){
    const int kin = kt * 128;                     // byte (=elem) offset in row

    __syncthreads();  // previous compute done before LDS overwrite
    // A: 32 chunks of 8 rows x 128B; wave stages 4
    #pragma unroll
    for (int j = 0; j < 4; ++j){
      const int rb = (wid * 4 + j) * 8;
      glds16(A8 + (size_t)(bm * 256 + rb + srow) * DDIM + kin + sslot * 16,
             sA + rb * 128);
    }
    // B: 16 chunks; wave stages 2
    #pragma unroll
    for (int i = 0; i < 2; ++i){
      const int rb = (wid * 2 + i) * 8;
      glds16(B8 + (size_t)(bn * 128 + rb + srow) * DDIM + kin + sslot * 16,
             sB + rb * 128);
    }
    __syncthreads();  // staging visible (compiler drains vmcnt before s_barrier)

    // 2 MFMA k-instances of 64 within the 128-K tile (proven b128 slot math)
    #pragma unroll
    for (int kk = 0; kk < 2; ++kk){
      i32x4 a[4], b[4];
      #pragma unroll
      for (int mf = 0; mf < 4; ++mf){
        const int r = wm * 64 + mf * 16 + l15;
        const int p = (kk * 4 + lk) ^ (r & 7);    // swizzled 16B slot
        a[mf] = *(const i32x4*)&sA[r * 128 + p * 16];
      }
      #pragma unroll
      for (int nf = 0; nf < 4; ++nf){
        const int r = wn * 64 + nf * 16 + l15;
        const int p = (kk * 4 + lk) ^ (r & 7);
        b[nf] = *(const i32x4*)&sB[r * 128 + p * 16];
      }
      #pragma unroll
      for (int mf = 0; mf < 4; ++mf)
        #pragma unroll
        for (int nf = 0; nf < 4; ++nf)
          acc[mf][nf] = __builtin_amdgcn_mfma_i32_16x16x64_i8(a[mf], b[nf], acc[mf][nf], 0, 0, 0);
    }
  }

  // ---- epilogue: per-(row,block) top-2 (quantized u32), two half-passes ----
  __syncthreads();                                 // loop's LDS reads done
  u32* mrg = (u32*)smem;                           // [128][68] u32 = 34816 B

  float csqv[4];
  u32 gcolv[4];
  #pragma unroll
  for (int nf = 0; nf < 4; ++nf){
    gcolv[nf] = bn * 128 + wn * 64 + nf * 16 + l15;
    csqv[nf]  = csq[gcolv[nf]];
  }
  #pragma unroll
  for (int H = 0; H < 2; ++H){
    if ((wm >> 1) == H){
      #pragma unroll
      for (int mf = 0; mf < 4; ++mf){
        #pragma unroll
        for (int r = 0; r < 4; ++r){
          const int lrow = (wm & 1) * 64 + mf * 16 + lk * 4 + r;  // 0..127 in half
          u32 b1 = 0xFFFFFFFFu, b2 = 0xFFFFFFFFu;
          #pragma unroll
          for (int nf = 0; nf < 4; ++nf){
            const float sc = csqv[nf] - TWO_INV_S2 * (float)acc[mf][nf][r];
            const u32 p = packQ(sc, gcolv[nf]);
            if (p < b1){ b2 = b1; b1 = p; } else if (p < b2){ b2 = p; }
          }
          *(uint2*)&mrg[lrow * 68 + (wn * 16 + l15) * 2] = make_uint2(b1, b2);
        }
      }
    }
    __syncthreads();
    if (tid < 128){
      u32 b1 = 0xFFFFFFFFu, b2 = 0xFFFFFFFFu;
      const uint4* rowp = (const uint4*)&mrg[tid * 68];
      #pragma unroll
      for (int j = 0; j < 16; ++j){
        const uint4 q = rowp[j];
        u32 vv[4] = {q.x, q.y, q.z, q.w};
        #pragma unroll
        for (int s = 0; s < 4; ++s){
          const u32 v = vv[s];
          if (v < b1){ b2 = b1; b1 = v; } else if (v < b2){ b2 = v; }
        }
      }
      blk2[(size_t)(bm * 256 + H * 128 + tid) * 64 + bn] = (u64)b1 | ((u64)b2 << 32);
    }
    __syncthreads();
  }
}

// ---- pass 2 (fused, proven R11/R12): extraction + exact refine + gather --
__global__ void refine_gather(const float* __restrict__ x, const float* __restrict__ cb,
                              const float* __restrict__ emb, const float* __restrict__ pe,
                              const float* __restrict__ csq,
                              const u64* __restrict__ blk2,
                              float* __restrict__ out){
  const int row = blockIdx.x, tid = threadIdx.x;
  const int wid = tid >> 6, lane = tid & 63;
  __shared__ u32 scand[8];
  __shared__ u32 scnt;
  __shared__ float red[4];
  __shared__ u32 swin;

  // wave 0: reduce 64 block-top-2s -> global min + candidates within MARGIN
  // (ascending extraction: the 8 approx-nearest always include the winner)
  if (wid == 0){
    const u64 v = blk2[(size_t)row * 64 + lane];
    u32 c1 = (u32)v, c2 = (u32)(v >> 32);
    float thr = 0.f;
    u32 count = 0;
    for (int k = 0; k < 8; ++k){
      u32 loc = (c1 < c2) ? c1 : c2;
      #pragma unroll
      for (int m = 1; m < 64; m <<= 1){
        const u32 o = __shfl_xor(loc, m, 64);
        loc = (o < loc) ? o : loc;
      }
      const float sf = unpackQ(loc);
      if (k == 0) thr = sf + MARGIN;
      else if (sf > thr) break;
      if (lane == 0) scand[k] = loc & 0x1FFFu;
      ++count;
      if (c1 == loc) c1 = 0xFFFFFFFFu;
      if (c2 == loc) c2 = 0xFFFFFFFFu;
    }
    if (lane == 0) scnt = count;
  }
  __syncthreads();

  u32 widx = scand[0];
  const u32 n = scnt;
  if (n > 1){
    const float4 xv = ((const float4*)x)[(size_t)row * 256 + tid];
    float bd2 = 0.f; u32 bidx = 0;
    for (u32 k = 0; k < n; ++k){
      const u32 c = scand[k];
      const float4 cv = ((const float4*)cb)[(size_t)c * 256 + tid];
      float p = xv.x*cv.x + xv.y*cv.y + xv.z*cv.z + xv.w*cv.w;
      #pragma unroll
      for (int m = 32; m; m >>= 1) p += __shfl_xor(p, m, 64);
      if (lane == 0) red[wid] = p;
      __syncthreads();
      if (tid == 0){
        const float d2 = csq[c] - 2.0f * (red[0] + red[1] + red[2] + red[3]);
        if (k == 0 || d2 < bd2 || (d2 == bd2 && c < bidx)){ bd2 = d2; bidx = c; }
        if (k == n - 1) swin = bidx;
      }
      __syncthreads();
    }
    widx = swin;
  }

  const int t = row & (TT - 1);
  const float4 e = ((const float4*)emb)[(size_t)widx * 256 + tid];
  const float4 p = ((const float4*)pe)[(size_t)t * 256 + tid];
  float4 o;
  o.x = e.x + p.x; o.y = e.y + p.y; o.z = e.z + p.z; o.w = e.w + p.w;
  ((float4*)out)[(size_t)row * 256 + tid] = o;
}

// ---- exact fp32 fallback (no workspace needed; slow but correct) ---------
__global__ void vq_fallback(const float* __restrict__ x, const float* __restrict__ cb,
                            const float* __restrict__ emb, const float* __restrict__ pe,
                            float* __restrict__ out){
  __shared__ float4 xs[256];
  __shared__ u64 red[256];
  const int row = blockIdx.x, tid = threadIdx.x;
  xs[tid] = ((const float4*)x)[(size_t)row * 256 + tid];
  __syncthreads();
  u64 best = ~0ull;
  for (int k = tid; k < KCODES; k += 256){
    const float4* c4 = (const float4*)(cb + (size_t)k * DDIM);
    float dot = 0.f, cs = 0.f;
    for (int j = 0; j < 256; ++j){
      float4 c = c4[j], xv = xs[j];
      dot += c.x * xv.x + c.y * xv.y + c.z * xv.z + c.w * xv.w;
      cs  += c.x * c.x + c.y * c.y + c.z * c.z + c.w * c.w;
    }
    u64 p = packScore(cs - 2.f * dot, (u32)k);
    best = (p < best) ? p : best;
  }
  red[tid] = best;
  __syncthreads();
  for (int s = 128; s; s >>= 1){
    if (tid < s && red[tid + s] < red[tid]) red[tid] = red[tid + s];
    __syncthreads();
  }
  const u32 idx = (u32)(red[0] & 0xFFFFFFFFu);
  const int t = row & (TT - 1);
  const float4 e = ((const float4*)emb)[(size_t)idx * 256 + tid];
  const float4 p = ((const float4*)pe)[(size_t)t * 256 + tid];
  float4 o;
  o.x = e.x + p.x; o.y = e.y + p.y; o.z = e.z + p.z; o.w = e.w + p.w;
  ((float4*)out)[(size_t)row * 256 + tid] = o;
}

// ---- launch --------------------------------------------------------------
extern "C" void kernel_launch(void* const* d_in, const int* in_sizes, int n_in,
                              void* d_out, int out_size, void* d_ws, size_t ws_size,
                              hipStream_t stream){
  const float* x   = (const float*)d_in[0];
  const float* cb  = (const float*)d_in[1];
  const float* emb = (const float*)d_in[2];
  const float* pe  = (const float*)d_in[3];
  float* out = (float*)d_out;

  const size_t OFF_CSQ  = 0;                         // 8192 * 4 B = 32 KB
  const size_t OFF_BLK2 = 32768;                     // 8192 * 64 * 8 B = 4 MB
  const size_t OFF_A8   = 32768 + 4194304;
  const size_t SEG      = (size_t)MROWS * DDIM;      // 8 MB (i8)
  const size_t NEEDED   = OFF_A8 + 2 * SEG;          // ~20.3 MB

  if (ws_size >= NEEDED){
    float* csq = (float*)((char*)d_ws + OFF_CSQ);
    u64* blk2 = (u64*)((char*)d_ws + OFF_BLK2);
    u8* A8 = (u8*)((char*)d_ws + OFF_A8);
    u8* B8 = A8 + SEG;

    hipLaunchKernelGGL(prep_all, dim3(MROWS + KCODES), dim3(256), 0, stream,
                       x, cb, A8, B8, csq);
    hipLaunchKernelGGL(vq_gemm, dim3(64, 32), dim3(512), 0, stream, A8, B8, csq, blk2);
    hipLaunchKernelGGL(refine_gather, dim3(MROWS), dim3(256), 0, stream,
                       x, cb, emb, pe, csq, blk2, out);
  } else {
    hipLaunchKernelGGL(vq_fallback, dim3(MROWS), dim3(256), 0, stream, x, cb, emb, pe, out);
  }
}